// Round 6
// baseline (481.533 us; speedup 1.0000x reference)
//
#include <hip/hip_runtime.h>

// ---------------------------------------------------------------------------
// EdgeNet: 2-layer GCN encode + dot-product edge decode, all fp32.
// R6: agg kernels restructured for memory-level parallelism:
//     - agg128: 2 edges/wave (half-wave x float4), unroll 4 -> 8 edges,
//       64 B/lane in flight; cross-half shfl_xor(32) reduce.
//     - agg64: 4 edges/wave (quarter-wave x float4), unroll 4 -> 16 edges.
//     GEMM: register-staged double buffer (global loads for tile k+1 issued
//     before compute on tile k).
// ---------------------------------------------------------------------------

#define SCAN_CH 512
#define BUK_SHIFT 7
#define BUK_NODES 128  // nodes per bucket

// --- edge bucketing -------------------------------------------------------
__global__ __launch_bounds__(256) void b_hist_k(const int* __restrict__ dst, int E,
                                                int nbuk, int* __restrict__ bhist) {
  __shared__ int h[1024];
  for (int i = threadIdx.x; i < nbuk; i += 256) h[i] = 0;
  __syncthreads();
  for (int i = blockIdx.x * 256 + threadIdx.x; i < E; i += gridDim.x * 256)
    atomicAdd(&h[dst[i] >> BUK_SHIFT], 1);
  __syncthreads();
  for (int i = threadIdx.x; i < nbuk; i += 256) {
    int c = h[i];
    if (c) atomicAdd(&bhist[i], c);
  }
}

__global__ __launch_bounds__(256) void b_scan_k(const int* __restrict__ bhist,
                                                int nbuk, int* __restrict__ bbase,
                                                int* __restrict__ bcur) {
  __shared__ int arr[256];
  const int t = threadIdx.x;
  const int per = (nbuk + 255) / 256;
  const int start = t * per;
  const int end = min(start + per, nbuk);
  int s = 0;
  for (int i = start; i < end; ++i) s += bhist[i];
  arr[t] = s;
  __syncthreads();
  for (int off = 1; off < 256; off <<= 1) {
    int v = (t >= off) ? arr[t - off] : 0;
    __syncthreads();
    arr[t] += v;
    __syncthreads();
  }
  int run = arr[t] - s;
  for (int i = start; i < end; ++i) {
    bbase[i] = run;
    bcur[i] = run;
    run += bhist[i];
  }
  if (t == 255) bbase[nbuk] = arr[255];
}

__global__ __launch_bounds__(256) void b_scatter_k(const int* __restrict__ src,
                                                   const int* __restrict__ dst, int E,
                                                   int nbuk, int* __restrict__ bcur,
                                                   int2* __restrict__ ebuf) {
  __shared__ int lh[1024];
  __shared__ int lc[1024];
  const int base = blockIdx.x * 8192;
  if (base >= E) return;
  const int end = min(base + 8192, E);
  for (int i = threadIdx.x; i < nbuk; i += 256) lh[i] = 0;
  __syncthreads();
  for (int i = base + threadIdx.x; i < end; i += 256)
    atomicAdd(&lh[dst[i] >> BUK_SHIFT], 1);
  __syncthreads();
  for (int i = threadIdx.x; i < nbuk; i += 256) {
    int c = lh[i];
    lc[i] = c ? atomicAdd(&bcur[i], c) : 0;
  }
  __syncthreads();
  for (int i = base + threadIdx.x; i < end; i += 256) {
    int d = dst[i];
    int pos = atomicAdd(&lc[d >> BUK_SHIFT], 1);
    ebuf[pos] = make_int2(src[i], d);
  }
}

__global__ __launch_bounds__(128) void b_deg_k(const int2* __restrict__ ebuf,
                                               const int* __restrict__ bbase, int n,
                                               int* __restrict__ deg,
                                               float* __restrict__ dinv) {
  __shared__ int cnt[BUK_NODES];
  const int b = blockIdx.x;
  cnt[threadIdx.x] = 0;
  __syncthreads();
  const int beg = bbase[b], end = bbase[b + 1];
  for (int i = beg + threadIdx.x; i < end; i += 128)
    atomicAdd(&cnt[ebuf[i].y & (BUK_NODES - 1)], 1);
  __syncthreads();
  const int node = (b << BUK_SHIFT) + threadIdx.x;
  if (node < n) {
    int c = cnt[threadIdx.x];
    deg[node] = c;
    dinv[node] = rsqrtf((float)(c + 1));  // +1 self-loop
  }
}

__global__ __launch_bounds__(128) void b_fill_k(const int2* __restrict__ ebuf,
                                                const int* __restrict__ bbase,
                                                const int* __restrict__ rowptr, int n,
                                                int* __restrict__ csr) {
  __shared__ int cur[BUK_NODES];
  const int b = blockIdx.x;
  const int node = (b << BUK_SHIFT) + threadIdx.x;
  cur[threadIdx.x] = (node < n) ? rowptr[node] : 0;
  __syncthreads();
  const int beg = bbase[b], end = bbase[b + 1];
  for (int i = beg + threadIdx.x; i < end; i += 128) {
    int2 e = ebuf[i];
    int pos = atomicAdd(&cur[e.y & (BUK_NODES - 1)], 1);
    csr[pos] = e.x;
  }
}

// --- 3-phase scan over node degrees -> rowptr -----------------------------
__global__ __launch_bounds__(256) void block_sum_k(const int* __restrict__ cnt, int n,
                                                   int* __restrict__ sums) {
  __shared__ int tsum[256];
  const int b = blockIdx.x, t = threadIdx.x;
  const int base = b * SCAN_CH + t * 2;
  int s = 0;
  if (base < n) s += cnt[base];
  if (base + 1 < n) s += cnt[base + 1];
  tsum[t] = s;
  __syncthreads();
  for (int off = 128; off > 0; off >>= 1) {
    if (t < off) tsum[t] += tsum[t + off];
    __syncthreads();
  }
  if (t == 0) sums[b] = tsum[0];
}

__global__ __launch_bounds__(256) void scan_sums_k(int* __restrict__ sums, int nb,
                                                   int n, int* __restrict__ rowptr) {
  __shared__ int arr[256];
  const int t = threadIdx.x;
  const int per = (nb + 255) / 256;
  const int start = t * per;
  const int end = min(start + per, nb);
  int s = 0;
  for (int i = start; i < end; ++i) s += sums[i];
  arr[t] = s;
  __syncthreads();
  for (int off = 1; off < 256; off <<= 1) {
    int v = (t >= off) ? arr[t - off] : 0;
    __syncthreads();
    arr[t] += v;
    __syncthreads();
  }
  int run = arr[t] - s;
  for (int i = start; i < end; ++i) {
    int c = sums[i];
    sums[i] = run;
    run += c;
  }
  if (t == 255) rowptr[n] = arr[255];
}

__global__ __launch_bounds__(256) void scan_fill_k(const int* __restrict__ cnt, int n,
                                                   const int* __restrict__ blockoff,
                                                   int* __restrict__ rowptr) {
  __shared__ int tsum[256];
  const int b = blockIdx.x, t = threadIdx.x;
  const int base = b * SCAN_CH + t * 2;
  const int c0 = (base < n) ? cnt[base] : 0;
  const int c1 = (base + 1 < n) ? cnt[base + 1] : 0;
  const int s = c0 + c1;
  tsum[t] = s;
  __syncthreads();
  for (int off = 1; off < 256; off <<= 1) {
    int v = (t >= off) ? tsum[t - off] : 0;
    __syncthreads();
    tsum[t] += v;
    __syncthreads();
  }
  const int pre = blockoff[b] + tsum[t] - s;
  if (base < n) rowptr[base] = pre;
  if (base + 1 < n) rowptr[base + 1] = pre + c0;
}

// ---------------------------------------------------------------------------
// fp32 tiled GEMM, C[M,N] = rowscale[m] * (A[M,K] @ B[K,N]).  BN == N.
// Register-staged double buffer: tile k+1 global loads issue before compute
// on tile k (latency hidden under the FMA loop).
// ---------------------------------------------------------------------------
template <int BM, int BN, int BK, int TM, int TN>
__global__ __launch_bounds__(256) void gemm_tiled(const float* __restrict__ A,
                                                  const float* __restrict__ B,
                                                  float* __restrict__ C,
                                                  const float* __restrict__ rowscale,
                                                  int M, int K, int N) {
  __shared__ float As[BK][BM + 4];
  __shared__ float Bs[BK][BN + 4];
  constexpr int AL = BM * BK / (4 * 256);
  constexpr int BL = BK * BN / (4 * 256);
  const int tid = threadIdx.x;
  const int tx = tid % (BN / TN);
  const int ty = tid / (BN / TN);
  const int rowBase = blockIdx.x * BM;

  float4 pa[AL], pb[BL];
  auto load_tile = [&](int k0) {
#pragma unroll
    for (int l = 0; l < AL; ++l) {
      const int idx = tid + l * 256;
      const int arow = idx / (BK / 4);
      const int acol = (idx % (BK / 4)) * 4;
      const int gr = rowBase + arow;
      pa[l] = (gr < M)
                  ? *reinterpret_cast<const float4*>(&A[(size_t)gr * K + k0 + acol])
                  : make_float4(0.f, 0.f, 0.f, 0.f);
    }
#pragma unroll
    for (int l = 0; l < BL; ++l) {
      const int idx = tid + l * 256;
      const int brow = idx / (BN / 4);
      const int bcol4 = (idx % (BN / 4)) * 4;
      pb[l] = *reinterpret_cast<const float4*>(&B[(size_t)(k0 + brow) * N + bcol4]);
    }
  };

  float acc[TM][TN];
#pragma unroll
  for (int i = 0; i < TM; ++i)
#pragma unroll
    for (int j = 0; j < TN; ++j) acc[i][j] = 0.f;

  load_tile(0);
  for (int k0 = 0; k0 < K; k0 += BK) {
#pragma unroll
    for (int l = 0; l < AL; ++l) {
      const int idx = tid + l * 256;
      const int arow = idx / (BK / 4);
      const int acol = (idx % (BK / 4)) * 4;
      As[acol + 0][arow] = pa[l].x;
      As[acol + 1][arow] = pa[l].y;
      As[acol + 2][arow] = pa[l].z;
      As[acol + 3][arow] = pa[l].w;
    }
#pragma unroll
    for (int l = 0; l < BL; ++l) {
      const int idx = tid + l * 256;
      const int brow = idx / (BN / 4);
      const int bcol4 = (idx % (BN / 4)) * 4;
      *reinterpret_cast<float4*>(&Bs[brow][bcol4]) = pb[l];
    }
    __syncthreads();
    if (k0 + BK < K) load_tile(k0 + BK);  // prefetch next tile (reg-staged)
#pragma unroll
    for (int kk = 0; kk < BK; ++kk) {
      float ra[TM], rb[TN];
#pragma unroll
      for (int i = 0; i < TM; i += 4)
        *reinterpret_cast<float4*>(&ra[i]) =
            *reinterpret_cast<const float4*>(&As[kk][ty * TM + i]);
#pragma unroll
      for (int j = 0; j < TN; j += 4)
        *reinterpret_cast<float4*>(&rb[j]) =
            *reinterpret_cast<const float4*>(&Bs[kk][tx * TN + j]);
#pragma unroll
      for (int i = 0; i < TM; ++i)
#pragma unroll
        for (int j = 0; j < TN; ++j) acc[i][j] += ra[i] * rb[j];
    }
    __syncthreads();
  }
#pragma unroll
  for (int i = 0; i < TM; ++i) {
    const int gr = rowBase + ty * TM + i;
    if (gr < M) {
      const float s = rowscale ? rowscale[gr] : 1.f;
#pragma unroll
      for (int j = 0; j < TN; j += 4) {
        float4 v = {acc[i][j] * s, acc[i][j + 1] * s, acc[i][j + 2] * s,
                    acc[i][j + 3] * s};
        *reinterpret_cast<float4*>(&C[(size_t)gr * N + tx * TN + j]) = v;
      }
    }
  }
}

// ---------------------------------------------------------------------------
// agg128: out[d] = RELU?( dinv[d]*(sum g[s] + g[d]) + bias ), C=128.
// Wave = 1 node; half-wave (32 lanes) x float4 covers a 512B row; the two
// halves process different edges -> 2 edges per step, unroll 4 -> 8 edges
// in flight (64 B/lane). Cross-half reduce via shfl_xor(32).
// ---------------------------------------------------------------------------
template <bool RELU>
__global__ __launch_bounds__(256) void agg128_k(const float* __restrict__ g,
                                                const int* __restrict__ rowptr,
                                                const int* __restrict__ csr,
                                                const float* __restrict__ dinv,
                                                const float* __restrict__ bias,
                                                float* __restrict__ hout, int n) {
  const int wid = (blockIdx.x * 256 + threadIdx.x) >> 6;
  if (wid >= n) return;
  const int lane = threadIdx.x & 63;
  const int half = lane >> 5;
  const size_t col = (size_t)(lane & 31) * 4;
  const float dd = dinv[wid];
  const int beg = rowptr[wid];
  const int end = rowptr[wid + 1];
  float4 acc = make_float4(0.f, 0.f, 0.f, 0.f);
  int e = beg;
  for (; e + 8 <= end; e += 8) {
    const int s0 = csr[e + 0 + half];
    const int s1 = csr[e + 2 + half];
    const int s2 = csr[e + 4 + half];
    const int s3 = csr[e + 6 + half];
    const float4 v0 = *reinterpret_cast<const float4*>(&g[(size_t)s0 * 128 + col]);
    const float4 v1 = *reinterpret_cast<const float4*>(&g[(size_t)s1 * 128 + col]);
    const float4 v2 = *reinterpret_cast<const float4*>(&g[(size_t)s2 * 128 + col]);
    const float4 v3 = *reinterpret_cast<const float4*>(&g[(size_t)s3 * 128 + col]);
    acc.x += (v0.x + v1.x) + (v2.x + v3.x);
    acc.y += (v0.y + v1.y) + (v2.y + v3.y);
    acc.z += (v0.z + v1.z) + (v2.z + v3.z);
    acc.w += (v0.w + v1.w) + (v2.w + v3.w);
  }
  for (; e + 2 <= end; e += 2) {
    const int s = csr[e + half];
    const float4 v = *reinterpret_cast<const float4*>(&g[(size_t)s * 128 + col]);
    acc.x += v.x;
    acc.y += v.y;
    acc.z += v.z;
    acc.w += v.w;
  }
  if (e < end && half == 0) {
    const int s = csr[e];
    const float4 v = *reinterpret_cast<const float4*>(&g[(size_t)s * 128 + col]);
    acc.x += v.x;
    acc.y += v.y;
    acc.z += v.z;
    acc.w += v.w;
  }
  acc.x += __shfl_xor(acc.x, 32);
  acc.y += __shfl_xor(acc.y, 32);
  acc.z += __shfl_xor(acc.z, 32);
  acc.w += __shfl_xor(acc.w, 32);
  if (half == 0) {
    const float4 sv = *reinterpret_cast<const float4*>(&g[(size_t)wid * 128 + col]);
    const float4 b = *reinterpret_cast<const float4*>(&bias[col]);
    float4 r;
    r.x = dd * (acc.x + sv.x) + b.x;
    r.y = dd * (acc.y + sv.y) + b.y;
    r.z = dd * (acc.z + sv.z) + b.z;
    r.w = dd * (acc.w + sv.w) + b.w;
    if (RELU) {
      r.x = fmaxf(r.x, 0.f);
      r.y = fmaxf(r.y, 0.f);
      r.z = fmaxf(r.z, 0.f);
      r.w = fmaxf(r.w, 0.f);
    }
    *reinterpret_cast<float4*>(&hout[(size_t)wid * 128 + col]) = r;
  }
}

// ---------------------------------------------------------------------------
// agg64: C=64. Quarter-wave (16 lanes) x float4 covers a 256B row -> 4 edges
// per step, unroll 4 -> 16 edges in flight. Reduce via shfl_xor(16), (32).
// ---------------------------------------------------------------------------
__global__ __launch_bounds__(256) void agg64_k(const float* __restrict__ g,
                                               const int* __restrict__ rowptr,
                                               const int* __restrict__ csr,
                                               const float* __restrict__ dinv,
                                               const float* __restrict__ bias,
                                               float* __restrict__ hout, int n) {
  const int wid = (blockIdx.x * 256 + threadIdx.x) >> 6;
  if (wid >= n) return;
  const int lane = threadIdx.x & 63;
  const int quad = lane >> 4;
  const size_t col = (size_t)(lane & 15) * 4;
  const float dd = dinv[wid];
  const int beg = rowptr[wid];
  const int end = rowptr[wid + 1];
  float4 acc = make_float4(0.f, 0.f, 0.f, 0.f);
  int e = beg;
  for (; e + 16 <= end; e += 16) {
    const int s0 = csr[e + 0 + quad];
    const int s1 = csr[e + 4 + quad];
    const int s2 = csr[e + 8 + quad];
    const int s3 = csr[e + 12 + quad];
    const float4 v0 = *reinterpret_cast<const float4*>(&g[(size_t)s0 * 64 + col]);
    const float4 v1 = *reinterpret_cast<const float4*>(&g[(size_t)s1 * 64 + col]);
    const float4 v2 = *reinterpret_cast<const float4*>(&g[(size_t)s2 * 64 + col]);
    const float4 v3 = *reinterpret_cast<const float4*>(&g[(size_t)s3 * 64 + col]);
    acc.x += (v0.x + v1.x) + (v2.x + v3.x);
    acc.y += (v0.y + v1.y) + (v2.y + v3.y);
    acc.z += (v0.z + v1.z) + (v2.z + v3.z);
    acc.w += (v0.w + v1.w) + (v2.w + v3.w);
  }
  for (; e + 4 <= end; e += 4) {
    const int s = csr[e + quad];
    const float4 v = *reinterpret_cast<const float4*>(&g[(size_t)s * 64 + col]);
    acc.x += v.x;
    acc.y += v.y;
    acc.z += v.z;
    acc.w += v.w;
  }
  const int r = end - e;  // 0..3
  if (quad < r) {
    const int s = csr[e + quad];
    const float4 v = *reinterpret_cast<const float4*>(&g[(size_t)s * 64 + col]);
    acc.x += v.x;
    acc.y += v.y;
    acc.z += v.z;
    acc.w += v.w;
  }
  acc.x += __shfl_xor(acc.x, 16);
  acc.y += __shfl_xor(acc.y, 16);
  acc.z += __shfl_xor(acc.z, 16);
  acc.w += __shfl_xor(acc.w, 16);
  acc.x += __shfl_xor(acc.x, 32);
  acc.y += __shfl_xor(acc.y, 32);
  acc.z += __shfl_xor(acc.z, 32);
  acc.w += __shfl_xor(acc.w, 32);
  if (quad == 0) {
    const float4 sv = *reinterpret_cast<const float4*>(&g[(size_t)wid * 64 + col]);
    const float4 b = *reinterpret_cast<const float4*>(&bias[col]);
    float4 res;
    res.x = dd * (acc.x + sv.x) + b.x;
    res.y = dd * (acc.y + sv.y) + b.y;
    res.z = dd * (acc.z + sv.z) + b.z;
    res.w = dd * (acc.w + sv.w) + b.w;
    *reinterpret_cast<float4*>(&hout[(size_t)wid * 64 + col]) = res;
  }
}

// ---------------------------------------------------------------------------
__global__ __launch_bounds__(256) void decode_k(const int* __restrict__ pos,
                                                const int* __restrict__ neg,
                                                const float* __restrict__ z,
                                                float* __restrict__ out, int EP) {
  const long long t = (long long)blockIdx.x * 256 + threadIdx.x;
  const long long e = t >> 4;
  const int lane = (int)(t & 15);
  if (e >= 2LL * EP) return;
  int u, v;
  if (e < EP) {
    u = pos[e];
    v = pos[EP + e];
  } else {
    u = neg[e - EP];
    v = neg[EP + (e - EP)];
  }
  const float4 a = *reinterpret_cast<const float4*>(&z[(size_t)u * 64 + lane * 4]);
  const float4 b = *reinterpret_cast<const float4*>(&z[(size_t)v * 64 + lane * 4]);
  float p = a.x * b.x + a.y * b.y + a.z * b.z + a.w * b.w;
#pragma unroll
  for (int off = 8; off > 0; off >>= 1) p += __shfl_down(p, off, 16);
  if (lane == 0) out[e] = p;
}

// ---------------------------------------------------------------------------

extern "C" void kernel_launch(void* const* d_in, const int* in_sizes, int n_in,
                              void* d_out, int out_size, void* d_ws, size_t ws_size,
                              hipStream_t stream) {
  const float* x = (const float*)d_in[0];
  const int* ei = (const int*)d_in[1];
  const int* pos = (const int*)d_in[2];
  const int* neg = (const int*)d_in[3];
  const float* W1 = (const float*)d_in[4];
  const float* b1 = (const float*)d_in[5];
  const float* W2 = (const float*)d_in[6];
  const float* b2 = (const float*)d_in[7];
  float* out = (float*)d_out;

  const int H = in_sizes[5];        // 128
  const int IN = in_sizes[4] / H;   // 256
  const int OUT = in_sizes[7];      // 64
  const int N = in_sizes[0] / IN;   // 100000
  const int E = in_sizes[1] / 2;    // 1600000
  const int EP = in_sizes[2] / 2;   // 500000

  char* ws = (char*)d_ws;
  size_t off = 0;
  auto carve = [&](size_t bytes) -> char* {
    char* p = ws + off;
    off += (bytes + 255) & ~(size_t)255;
    return p;
  };
  const int NB = (N + SCAN_CH - 1) / SCAN_CH;
  const int NBUK = (N + BUK_NODES - 1) >> BUK_SHIFT;  // 782

  int* degi = (int*)carve((size_t)N * 4);
  float* dinvb = (float*)carve((size_t)N * 4);
  int* rowptr = (int*)carve((size_t)(N + 1) * 4);
  int* bsums = (int*)carve((size_t)NB * 4);
  int* bhist = (int*)carve((size_t)NBUK * 4);
  int* bbase = (int*)carve((size_t)(NBUK + 1) * 4);
  int* bcur = (int*)carve((size_t)NBUK * 4);
  int2* ebuf = (int2*)carve((size_t)E * 8);
  int* csr = (int*)carve((size_t)E * 4);
  float* bufA = (float*)carve((size_t)N * H * 4);
  float* bufB = (float*)carve((size_t)N * H * 4);
  (void)ws_size;

  const int* srcp = ei;
  const int* dstp = ei + E;

  // --- CSR build via bucketing ---
  hipMemsetAsync(bhist, 0, (size_t)NBUK * 4, stream);
  b_hist_k<<<512, 256, 0, stream>>>(dstp, E, NBUK, bhist);
  b_scan_k<<<1, 256, 0, stream>>>(bhist, NBUK, bbase, bcur);
  b_scatter_k<<<(E + 8191) / 8192, 256, 0, stream>>>(srcp, dstp, E, NBUK, bcur, ebuf);
  b_deg_k<<<NBUK, 128, 0, stream>>>(ebuf, bbase, N, degi, dinvb);
  block_sum_k<<<NB, 256, 0, stream>>>(degi, N, bsums);
  scan_sums_k<<<1, 256, 0, stream>>>(bsums, NB, N, rowptr);
  scan_fill_k<<<NB, 256, 0, stream>>>(degi, N, bsums, rowptr);
  b_fill_k<<<NBUK, 128, 0, stream>>>(ebuf, bbase, rowptr, N, csr);

  // --- encode ---
  gemm_tiled<64, 128, 32, 8, 4>
      <<<(N + 63) / 64, 256, 0, stream>>>(x, W1, bufA, dinvb, N, IN, H);
  agg128_k<true><<<(N + 3) / 4, 256, 0, stream>>>(bufA, rowptr, csr, dinvb, b1,
                                                  bufB, N);
  gemm_tiled<64, 64, 32, 4, 4>
      <<<(N + 63) / 64, 256, 0, stream>>>(bufB, W2, bufA, dinvb, N, H, OUT);
  agg64_k<<<(N + 3) / 4, 256, 0, stream>>>(bufA, rowptr, csr, dinvb, b2, bufB, N);
  // --- decode ---
  const long long threads = 2LL * EP * 16;
  decode_k<<<(int)((threads + 255) / 256), 256, 0, stream>>>(pos, neg, bufB, out, EP);
}

// Round 7
// 471.990 us; speedup vs baseline: 1.0202x; 1.0202x over previous
//
#include <hip/hip_runtime.h>

// ---------------------------------------------------------------------------
// EdgeNet: 2-layer GCN encode + dot-product edge decode, all fp32.
// R7: (a) GEMM un-spilled: no reg prefetch (R6's spilled 128MB to scratch),
//     8x8 micro-tile @ 128 threads (2x FMA per LDS read), BK=16 (12.8KB LDS),
//     __launch_bounds__(NT,4) so compiler targets 128 VGPR (no spill-at-64).
//     (b) rowptr computed inside b_deg_k (bucket base + in-bucket scan);
//     deletes the 3-kernel global scan chain.
// ---------------------------------------------------------------------------

#define BUK_SHIFT 7
#define BUK_NODES 128  // nodes per bucket

// --- edge bucketing -------------------------------------------------------
__global__ __launch_bounds__(256) void b_hist_k(const int* __restrict__ dst, int E,
                                                int nbuk, int* __restrict__ bhist) {
  __shared__ int h[1024];
  for (int i = threadIdx.x; i < nbuk; i += 256) h[i] = 0;
  __syncthreads();
  for (int i = blockIdx.x * 256 + threadIdx.x; i < E; i += gridDim.x * 256)
    atomicAdd(&h[dst[i] >> BUK_SHIFT], 1);
  __syncthreads();
  for (int i = threadIdx.x; i < nbuk; i += 256) {
    int c = h[i];
    if (c) atomicAdd(&bhist[i], c);
  }
}

__global__ __launch_bounds__(256) void b_scan_k(const int* __restrict__ bhist,
                                                int nbuk, int* __restrict__ bbase,
                                                int* __restrict__ bcur) {
  __shared__ int arr[256];
  const int t = threadIdx.x;
  const int per = (nbuk + 255) / 256;
  const int start = t * per;
  const int end = min(start + per, nbuk);
  int s = 0;
  for (int i = start; i < end; ++i) s += bhist[i];
  arr[t] = s;
  __syncthreads();
  for (int off = 1; off < 256; off <<= 1) {
    int v = (t >= off) ? arr[t - off] : 0;
    __syncthreads();
    arr[t] += v;
    __syncthreads();
  }
  int run = arr[t] - s;
  for (int i = start; i < end; ++i) {
    bbase[i] = run;
    bcur[i] = run;
    run += bhist[i];
  }
  if (t == 255) bbase[nbuk] = arr[255];
}

__global__ __launch_bounds__(256) void b_scatter_k(const int* __restrict__ src,
                                                   const int* __restrict__ dst, int E,
                                                   int nbuk, int* __restrict__ bcur,
                                                   int2* __restrict__ ebuf) {
  __shared__ int lh[1024];
  __shared__ int lc[1024];
  const int base = blockIdx.x * 8192;
  if (base >= E) return;
  const int end = min(base + 8192, E);
  for (int i = threadIdx.x; i < nbuk; i += 256) lh[i] = 0;
  __syncthreads();
  for (int i = base + threadIdx.x; i < end; i += 256)
    atomicAdd(&lh[dst[i] >> BUK_SHIFT], 1);
  __syncthreads();
  for (int i = threadIdx.x; i < nbuk; i += 256) {
    int c = lh[i];
    lc[i] = c ? atomicAdd(&bcur[i], c) : 0;
  }
  __syncthreads();
  for (int i = base + threadIdx.x; i < end; i += 256) {
    int d = dst[i];
    int pos = atomicAdd(&lc[d >> BUK_SHIFT], 1);
    ebuf[pos] = make_int2(src[i], d);
  }
}

// one block per bucket: degree count + in-bucket scan -> rowptr + dinv.
// Buckets are 128 CONTIGUOUS node ids, so rowptr[node] = bbase[bucket] +
// exclusive-prefix-within-bucket (global scan not needed).
__global__ __launch_bounds__(128) void b_deg_k(const int2* __restrict__ ebuf,
                                               const int* __restrict__ bbase, int n,
                                               int nbuk, float* __restrict__ dinv,
                                               int* __restrict__ rowptr) {
  __shared__ int cnt[BUK_NODES];
  __shared__ int pre[BUK_NODES];
  const int b = blockIdx.x, t = threadIdx.x;
  cnt[t] = 0;
  __syncthreads();
  const int beg = bbase[b], end = bbase[b + 1];
  for (int i = beg + t; i < end; i += 128)
    atomicAdd(&cnt[ebuf[i].y & (BUK_NODES - 1)], 1);
  __syncthreads();
  const int c = cnt[t];
  pre[t] = c;
  __syncthreads();
  for (int off = 1; off < 128; off <<= 1) {
    int v = (t >= off) ? pre[t - off] : 0;
    __syncthreads();
    pre[t] += v;
    __syncthreads();
  }
  const int node = (b << BUK_SHIFT) + t;
  if (node < n) {
    rowptr[node] = bbase[b] + pre[t] - c;  // exclusive prefix
    dinv[node] = rsqrtf((float)(c + 1));   // +1 self-loop
  }
  if (b == 0 && t == 0) rowptr[n] = bbase[nbuk];  // == E
}

// one block per bucket: CSR fill with LDS cursors (no global atomics)
__global__ __launch_bounds__(128) void b_fill_k(const int2* __restrict__ ebuf,
                                                const int* __restrict__ bbase,
                                                const int* __restrict__ rowptr, int n,
                                                int* __restrict__ csr) {
  __shared__ int cur[BUK_NODES];
  const int b = blockIdx.x;
  const int node = (b << BUK_SHIFT) + threadIdx.x;
  cur[threadIdx.x] = (node < n) ? rowptr[node] : 0;
  __syncthreads();
  const int beg = bbase[b], end = bbase[b + 1];
  for (int i = beg + threadIdx.x; i < end; i += 128) {
    int2 e = ebuf[i];
    int pos = atomicAdd(&cur[e.y & (BUK_NODES - 1)], 1);
    csr[pos] = e.x;
  }
}

// ---------------------------------------------------------------------------
// fp32 tiled GEMM, C[M,N] = rowscale[m] * (A[M,K] @ B[K,N]).  BN == N.
// NT threads = (BM/TM)*(BN/TN). As transposed [BK][BM+4]; Bs [BK][BN+4].
// ---------------------------------------------------------------------------
template <int BM, int BN, int BK, int TM, int TN, int NT>
__global__ __launch_bounds__(NT, 4) void gemm_tiled(const float* __restrict__ A,
                                                    const float* __restrict__ B,
                                                    float* __restrict__ C,
                                                    const float* __restrict__ rowscale,
                                                    int M, int K, int N) {
  static_assert(NT == (BM / TM) * (BN / TN), "thread count");
  __shared__ float As[BK][BM + 4];
  __shared__ float Bs[BK][BN + 4];
  constexpr int AL = BM * BK / (4 * NT);
  constexpr int BL = BK * BN / (4 * NT);
  const int tid = threadIdx.x;
  const int tx = tid % (BN / TN);
  const int ty = tid / (BN / TN);
  const int rowBase = blockIdx.x * BM;

  float acc[TM][TN];
#pragma unroll
  for (int i = 0; i < TM; ++i)
#pragma unroll
    for (int j = 0; j < TN; ++j) acc[i][j] = 0.f;

  for (int k0 = 0; k0 < K; k0 += BK) {
#pragma unroll
    for (int l = 0; l < AL; ++l) {
      const int idx = tid + l * NT;
      const int arow = idx / (BK / 4);
      const int acol = (idx % (BK / 4)) * 4;
      const int gr = rowBase + arow;
      float4 v;
      if (gr < M)
        v = *reinterpret_cast<const float4*>(&A[(size_t)gr * K + k0 + acol]);
      else
        v = make_float4(0.f, 0.f, 0.f, 0.f);
      As[acol + 0][arow] = v.x;
      As[acol + 1][arow] = v.y;
      As[acol + 2][arow] = v.z;
      As[acol + 3][arow] = v.w;
    }
#pragma unroll
    for (int l = 0; l < BL; ++l) {
      const int idx = tid + l * NT;
      const int brow = idx / (BN / 4);
      const int bcol4 = (idx % (BN / 4)) * 4;
      *reinterpret_cast<float4*>(&Bs[brow][bcol4]) =
          *reinterpret_cast<const float4*>(&B[(size_t)(k0 + brow) * N + bcol4]);
    }
    __syncthreads();
#pragma unroll
    for (int kk = 0; kk < BK; ++kk) {
      float ra[TM], rb[TN];
#pragma unroll
      for (int i = 0; i < TM; i += 4)
        *reinterpret_cast<float4*>(&ra[i]) =
            *reinterpret_cast<const float4*>(&As[kk][ty * TM + i]);
#pragma unroll
      for (int j = 0; j < TN; j += 4)
        *reinterpret_cast<float4*>(&rb[j]) =
            *reinterpret_cast<const float4*>(&Bs[kk][tx * TN + j]);
#pragma unroll
      for (int i = 0; i < TM; ++i)
#pragma unroll
        for (int j = 0; j < TN; ++j) acc[i][j] += ra[i] * rb[j];
    }
    __syncthreads();
  }
#pragma unroll
  for (int i = 0; i < TM; ++i) {
    const int gr = rowBase + ty * TM + i;
    if (gr < M) {
      const float s = rowscale[gr];
#pragma unroll
      for (int j = 0; j < TN; j += 4) {
        float4 v = {acc[i][j] * s, acc[i][j + 1] * s, acc[i][j + 2] * s,
                    acc[i][j + 3] * s};
        *reinterpret_cast<float4*>(&C[(size_t)gr * N + tx * TN + j]) = v;
      }
    }
  }
}

// ---------------------------------------------------------------------------
// agg128: out[d] = RELU?( dinv[d]*(sum g[s] + g[d]) + bias ), C=128.
// Half-wave x float4; two halves take different edges; unroll 4 -> 8 edges
// in flight. Cross-half reduce via shfl_xor(32).
// ---------------------------------------------------------------------------
template <bool RELU>
__global__ __launch_bounds__(256) void agg128_k(const float* __restrict__ g,
                                                const int* __restrict__ rowptr,
                                                const int* __restrict__ csr,
                                                const float* __restrict__ dinv,
                                                const float* __restrict__ bias,
                                                float* __restrict__ hout, int n) {
  const int wid = (blockIdx.x * 256 + threadIdx.x) >> 6;
  if (wid >= n) return;
  const int lane = threadIdx.x & 63;
  const int half = lane >> 5;
  const size_t col = (size_t)(lane & 31) * 4;
  const float dd = dinv[wid];
  const int beg = rowptr[wid];
  const int end = rowptr[wid + 1];
  float4 acc = make_float4(0.f, 0.f, 0.f, 0.f);
  int e = beg;
  for (; e + 8 <= end; e += 8) {
    const int s0 = csr[e + 0 + half];
    const int s1 = csr[e + 2 + half];
    const int s2 = csr[e + 4 + half];
    const int s3 = csr[e + 6 + half];
    const float4 v0 = *reinterpret_cast<const float4*>(&g[(size_t)s0 * 128 + col]);
    const float4 v1 = *reinterpret_cast<const float4*>(&g[(size_t)s1 * 128 + col]);
    const float4 v2 = *reinterpret_cast<const float4*>(&g[(size_t)s2 * 128 + col]);
    const float4 v3 = *reinterpret_cast<const float4*>(&g[(size_t)s3 * 128 + col]);
    acc.x += (v0.x + v1.x) + (v2.x + v3.x);
    acc.y += (v0.y + v1.y) + (v2.y + v3.y);
    acc.z += (v0.z + v1.z) + (v2.z + v3.z);
    acc.w += (v0.w + v1.w) + (v2.w + v3.w);
  }
  for (; e + 2 <= end; e += 2) {
    const int s = csr[e + half];
    const float4 v = *reinterpret_cast<const float4*>(&g[(size_t)s * 128 + col]);
    acc.x += v.x;
    acc.y += v.y;
    acc.z += v.z;
    acc.w += v.w;
  }
  if (e < end && half == 0) {
    const int s = csr[e];
    const float4 v = *reinterpret_cast<const float4*>(&g[(size_t)s * 128 + col]);
    acc.x += v.x;
    acc.y += v.y;
    acc.z += v.z;
    acc.w += v.w;
  }
  acc.x += __shfl_xor(acc.x, 32);
  acc.y += __shfl_xor(acc.y, 32);
  acc.z += __shfl_xor(acc.z, 32);
  acc.w += __shfl_xor(acc.w, 32);
  if (half == 0) {
    const float4 sv = *reinterpret_cast<const float4*>(&g[(size_t)wid * 128 + col]);
    const float4 b = *reinterpret_cast<const float4*>(&bias[col]);
    float4 r;
    r.x = dd * (acc.x + sv.x) + b.x;
    r.y = dd * (acc.y + sv.y) + b.y;
    r.z = dd * (acc.z + sv.z) + b.z;
    r.w = dd * (acc.w + sv.w) + b.w;
    if (RELU) {
      r.x = fmaxf(r.x, 0.f);
      r.y = fmaxf(r.y, 0.f);
      r.z = fmaxf(r.z, 0.f);
      r.w = fmaxf(r.w, 0.f);
    }
    *reinterpret_cast<float4*>(&hout[(size_t)wid * 128 + col]) = r;
  }
}

// ---------------------------------------------------------------------------
// agg64: C=64. Quarter-wave x float4 -> 4 edges/step, unroll 4 -> 16 edges.
// ---------------------------------------------------------------------------
__global__ __launch_bounds__(256) void agg64_k(const float* __restrict__ g,
                                               const int* __restrict__ rowptr,
                                               const int* __restrict__ csr,
                                               const float* __restrict__ dinv,
                                               const float* __restrict__ bias,
                                               float* __restrict__ hout, int n) {
  const int wid = (blockIdx.x * 256 + threadIdx.x) >> 6;
  if (wid >= n) return;
  const int lane = threadIdx.x & 63;
  const int quad = lane >> 4;
  const size_t col = (size_t)(lane & 15) * 4;
  const float dd = dinv[wid];
  const int beg = rowptr[wid];
  const int end = rowptr[wid + 1];
  float4 acc = make_float4(0.f, 0.f, 0.f, 0.f);
  int e = beg;
  for (; e + 16 <= end; e += 16) {
    const int s0 = csr[e + 0 + quad];
    const int s1 = csr[e + 4 + quad];
    const int s2 = csr[e + 8 + quad];
    const int s3 = csr[e + 12 + quad];
    const float4 v0 = *reinterpret_cast<const float4*>(&g[(size_t)s0 * 64 + col]);
    const float4 v1 = *reinterpret_cast<const float4*>(&g[(size_t)s1 * 64 + col]);
    const float4 v2 = *reinterpret_cast<const float4*>(&g[(size_t)s2 * 64 + col]);
    const float4 v3 = *reinterpret_cast<const float4*>(&g[(size_t)s3 * 64 + col]);
    acc.x += (v0.x + v1.x) + (v2.x + v3.x);
    acc.y += (v0.y + v1.y) + (v2.y + v3.y);
    acc.z += (v0.z + v1.z) + (v2.z + v3.z);
    acc.w += (v0.w + v1.w) + (v2.w + v3.w);
  }
  for (; e + 4 <= end; e += 4) {
    const int s = csr[e + quad];
    const float4 v = *reinterpret_cast<const float4*>(&g[(size_t)s * 64 + col]);
    acc.x += v.x;
    acc.y += v.y;
    acc.z += v.z;
    acc.w += v.w;
  }
  const int r = end - e;  // 0..3
  if (quad < r) {
    const int s = csr[e + quad];
    const float4 v = *reinterpret_cast<const float4*>(&g[(size_t)s * 64 + col]);
    acc.x += v.x;
    acc.y += v.y;
    acc.z += v.z;
    acc.w += v.w;
  }
  acc.x += __shfl_xor(acc.x, 16);
  acc.y += __shfl_xor(acc.y, 16);
  acc.z += __shfl_xor(acc.z, 16);
  acc.w += __shfl_xor(acc.w, 16);
  acc.x += __shfl_xor(acc.x, 32);
  acc.y += __shfl_xor(acc.y, 32);
  acc.z += __shfl_xor(acc.z, 32);
  acc.w += __shfl_xor(acc.w, 32);
  if (quad == 0) {
    const float4 sv = *reinterpret_cast<const float4*>(&g[(size_t)wid * 64 + col]);
    const float4 b = *reinterpret_cast<const float4*>(&bias[col]);
    float4 res;
    res.x = dd * (acc.x + sv.x) + b.x;
    res.y = dd * (acc.y + sv.y) + b.y;
    res.z = dd * (acc.z + sv.z) + b.z;
    res.w = dd * (acc.w + sv.w) + b.w;
    *reinterpret_cast<float4*>(&hout[(size_t)wid * 64 + col]) = res;
  }
}

// ---------------------------------------------------------------------------
__global__ __launch_bounds__(256) void decode_k(const int* __restrict__ pos,
                                                const int* __restrict__ neg,
                                                const float* __restrict__ z,
                                                float* __restrict__ out, int EP) {
  const long long t = (long long)blockIdx.x * 256 + threadIdx.x;
  const long long e = t >> 4;
  const int lane = (int)(t & 15);
  if (e >= 2LL * EP) return;
  int u, v;
  if (e < EP) {
    u = pos[e];
    v = pos[EP + e];
  } else {
    u = neg[e - EP];
    v = neg[EP + (e - EP)];
  }
  const float4 a = *reinterpret_cast<const float4*>(&z[(size_t)u * 64 + lane * 4]);
  const float4 b = *reinterpret_cast<const float4*>(&z[(size_t)v * 64 + lane * 4]);
  float p = a.x * b.x + a.y * b.y + a.z * b.z + a.w * b.w;
#pragma unroll
  for (int off = 8; off > 0; off >>= 1) p += __shfl_down(p, off, 16);
  if (lane == 0) out[e] = p;
}

// ---------------------------------------------------------------------------

extern "C" void kernel_launch(void* const* d_in, const int* in_sizes, int n_in,
                              void* d_out, int out_size, void* d_ws, size_t ws_size,
                              hipStream_t stream) {
  const float* x = (const float*)d_in[0];
  const int* ei = (const int*)d_in[1];
  const int* pos = (const int*)d_in[2];
  const int* neg = (const int*)d_in[3];
  const float* W1 = (const float*)d_in[4];
  const float* b1 = (const float*)d_in[5];
  const float* W2 = (const float*)d_in[6];
  const float* b2 = (const float*)d_in[7];
  float* out = (float*)d_out;

  const int H = in_sizes[5];        // 128
  const int IN = in_sizes[4] / H;   // 256
  const int OUT = in_sizes[7];      // 64
  const int N = in_sizes[0] / IN;   // 100000
  const int E = in_sizes[1] / 2;    // 1600000
  const int EP = in_sizes[2] / 2;   // 500000

  char* ws = (char*)d_ws;
  size_t off = 0;
  auto carve = [&](size_t bytes) -> char* {
    char* p = ws + off;
    off += (bytes + 255) & ~(size_t)255;
    return p;
  };
  const int NBUK = (N + BUK_NODES - 1) >> BUK_SHIFT;  // 782

  float* dinvb = (float*)carve((size_t)N * 4);
  int* rowptr = (int*)carve((size_t)(N + 1) * 4);
  int* bhist = (int*)carve((size_t)NBUK * 4);
  int* bbase = (int*)carve((size_t)(NBUK + 1) * 4);
  int* bcur = (int*)carve((size_t)NBUK * 4);
  int2* ebuf = (int2*)carve((size_t)E * 8);
  int* csr = (int*)carve((size_t)E * 4);
  float* bufA = (float*)carve((size_t)N * H * 4);
  float* bufB = (float*)carve((size_t)N * H * 4);
  (void)ws_size;

  const int* srcp = ei;
  const int* dstp = ei + E;

  // --- CSR build via bucketing (rowptr fused into b_deg_k) ---
  hipMemsetAsync(bhist, 0, (size_t)NBUK * 4, stream);
  b_hist_k<<<512, 256, 0, stream>>>(dstp, E, NBUK, bhist);
  b_scan_k<<<1, 256, 0, stream>>>(bhist, NBUK, bbase, bcur);
  b_scatter_k<<<(E + 8191) / 8192, 256, 0, stream>>>(srcp, dstp, E, NBUK, bcur, ebuf);
  b_deg_k<<<NBUK, 128, 0, stream>>>(ebuf, bbase, N, NBUK, dinvb, rowptr);
  b_fill_k<<<NBUK, 128, 0, stream>>>(ebuf, bbase, rowptr, N, csr);

  // --- encode ---
  gemm_tiled<64, 128, 16, 8, 8, 128>
      <<<(N + 63) / 64, 128, 0, stream>>>(x, W1, bufA, dinvb, N, IN, H);
  agg128_k<true><<<(N + 3) / 4, 256, 0, stream>>>(bufA, rowptr, csr, dinvb, b1,
                                                  bufB, N);
  gemm_tiled<64, 64, 32, 4, 4, 256>
      <<<(N + 63) / 64, 256, 0, stream>>>(bufB, W2, bufA, dinvb, N, H, OUT);
  agg64_k<<<(N + 3) / 4, 256, 0, stream>>>(bufA, rowptr, csr, dinvb, b2, bufB, N);
  // --- decode ---
  const long long threads = 2LL * EP * 16;
  decode_k<<<(int)((threads + 255) / 256), 256, 0, stream>>>(pos, neg, bufB, out, EP);
}

// Round 8
// 434.276 us; speedup vs baseline: 1.1088x; 1.0868x over previous
//
#include <hip/hip_runtime.h>

// ---------------------------------------------------------------------------
// EdgeNet: 2-layer GCN encode + dot-product edge decode, all fp32.
// R8: GEMMs reverted to R5 config (TM8xTN4 / TM4xTN4, 256thr, no min-wave
//     bound -> no spill, TN=4 read pattern = 2.4M not 7.2M conflicts).
//     CSR: b_deg+b_fill fused into b_build_k; ebuf packed to 1 int
//     (src | (dst&127)<<17). Decode: 8 lanes/edge, 2x float4 per lane.
// ---------------------------------------------------------------------------

#define BUK_SHIFT 7
#define BUK_NODES 128  // nodes per bucket

// --- edge bucketing -------------------------------------------------------
__global__ __launch_bounds__(256) void b_hist_k(const int* __restrict__ dst, int E,
                                                int nbuk, int* __restrict__ bhist) {
  __shared__ int h[1024];
  for (int i = threadIdx.x; i < nbuk; i += 256) h[i] = 0;
  __syncthreads();
  for (int i = blockIdx.x * 256 + threadIdx.x; i < E; i += gridDim.x * 256)
    atomicAdd(&h[dst[i] >> BUK_SHIFT], 1);
  __syncthreads();
  for (int i = threadIdx.x; i < nbuk; i += 256) {
    int c = h[i];
    if (c) atomicAdd(&bhist[i], c);
  }
}

__global__ __launch_bounds__(256) void b_scan_k(const int* __restrict__ bhist,
                                                int nbuk, int* __restrict__ bbase,
                                                int* __restrict__ bcur) {
  __shared__ int arr[256];
  const int t = threadIdx.x;
  const int per = (nbuk + 255) / 256;
  const int start = t * per;
  const int end = min(start + per, nbuk);
  int s = 0;
  for (int i = start; i < end; ++i) s += bhist[i];
  arr[t] = s;
  __syncthreads();
  for (int off = 1; off < 256; off <<= 1) {
    int v = (t >= off) ? arr[t - off] : 0;
    __syncthreads();
    arr[t] += v;
    __syncthreads();
  }
  int run = arr[t] - s;
  for (int i = start; i < end; ++i) {
    bbase[i] = run;
    bcur[i] = run;
    run += bhist[i];
  }
  if (t == 255) bbase[nbuk] = arr[255];
}

// chunk of 8192 edges per block; LDS hist -> reserve -> scatter packed ints
__global__ __launch_bounds__(256) void b_scatter_k(const int* __restrict__ src,
                                                   const int* __restrict__ dst, int E,
                                                   int nbuk, int* __restrict__ bcur,
                                                   int* __restrict__ ebuf) {
  __shared__ int lh[1024];
  __shared__ int lc[1024];
  const int base = blockIdx.x * 8192;
  if (base >= E) return;
  const int end = min(base + 8192, E);
  for (int i = threadIdx.x; i < nbuk; i += 256) lh[i] = 0;
  __syncthreads();
  for (int i = base + threadIdx.x; i < end; i += 256)
    atomicAdd(&lh[dst[i] >> BUK_SHIFT], 1);
  __syncthreads();
  for (int i = threadIdx.x; i < nbuk; i += 256) {
    int c = lh[i];
    lc[i] = c ? atomicAdd(&bcur[i], c) : 0;
  }
  __syncthreads();
  for (int i = base + threadIdx.x; i < end; i += 256) {
    int d = dst[i];
    int pos = atomicAdd(&lc[d >> BUK_SHIFT], 1);
    ebuf[pos] = src[i] | ((d & (BUK_NODES - 1)) << 17);  // src < 2^17
  }
}

// one block per bucket: count -> LDS scan -> rowptr/dinv -> CSR fill.
// Buckets are 128 contiguous node ids: rowptr[node] = bbase[b] + in-bucket
// exclusive prefix. Second ebuf pass is L2-hot (~16KB/bucket).
__global__ __launch_bounds__(128) void b_build_k(const int* __restrict__ ebuf,
                                                 const int* __restrict__ bbase, int n,
                                                 int nbuk, float* __restrict__ dinv,
                                                 int* __restrict__ rowptr,
                                                 int* __restrict__ csr) {
  __shared__ int cnt[BUK_NODES];
  __shared__ int pre[BUK_NODES];
  __shared__ int cur[BUK_NODES];
  const int b = blockIdx.x, t = threadIdx.x;
  cnt[t] = 0;
  __syncthreads();
  const int beg = bbase[b], end = bbase[b + 1];
  for (int i = beg + t; i < end; i += 128) atomicAdd(&cnt[ebuf[i] >> 17], 1);
  __syncthreads();
  const int c = cnt[t];
  pre[t] = c;
  __syncthreads();
  for (int off = 1; off < 128; off <<= 1) {
    int v = (t >= off) ? pre[t - off] : 0;
    __syncthreads();
    pre[t] += v;
    __syncthreads();
  }
  const int base = beg + pre[t] - c;  // exclusive prefix + bucket base
  cur[t] = base;
  const int node = (b << BUK_SHIFT) + t;
  if (node < n) {
    rowptr[node] = base;
    dinv[node] = rsqrtf((float)(c + 1));  // +1 self-loop
  }
  if (b == 0 && t == 0) rowptr[n] = bbase[nbuk];
  __syncthreads();
  for (int i = beg + t; i < end; i += 128) {
    int e = ebuf[i];
    int pos = atomicAdd(&cur[e >> 17], 1);
    csr[pos] = e & 0x1FFFF;
  }
}

// ---------------------------------------------------------------------------
// fp32 tiled GEMM, C[M,N] = rowscale[m] * (A[M,K] @ B[K,N]).  BN == N.
// R5-proven config. As transposed [BK][BM+4]; Bs [BK][BN+4]; TN=4 so a
// wave's rb b128 reads span the full Bs row (clean pattern).
// ---------------------------------------------------------------------------
template <int BM, int BN, int BK, int TM, int TN>
__global__ __launch_bounds__(256) void gemm_tiled(const float* __restrict__ A,
                                                  const float* __restrict__ B,
                                                  float* __restrict__ C,
                                                  const float* __restrict__ rowscale,
                                                  int M, int K, int N) {
  __shared__ float As[BK][BM + 4];
  __shared__ float Bs[BK][BN + 4];
  const int tid = threadIdx.x;
  const int tx = tid % (BN / TN);
  const int ty = tid / (BN / TN);
  const int rowBase = blockIdx.x * BM;

  float acc[TM][TN];
#pragma unroll
  for (int i = 0; i < TM; ++i)
#pragma unroll
    for (int j = 0; j < TN; ++j) acc[i][j] = 0.f;

  for (int k0 = 0; k0 < K; k0 += BK) {
#pragma unroll
    for (int l = 0; l < BM * BK / (4 * 256); ++l) {
      const int idx = tid + l * 256;
      const int arow = idx / (BK / 4);
      const int acol = (idx % (BK / 4)) * 4;
      const int gr = rowBase + arow;
      float4 v;
      if (gr < M)
        v = *reinterpret_cast<const float4*>(&A[(size_t)gr * K + k0 + acol]);
      else
        v = make_float4(0.f, 0.f, 0.f, 0.f);
      As[acol + 0][arow] = v.x;
      As[acol + 1][arow] = v.y;
      As[acol + 2][arow] = v.z;
      As[acol + 3][arow] = v.w;
    }
#pragma unroll
    for (int l = 0; l < BK * BN / (4 * 256); ++l) {
      const int idx = tid + l * 256;
      const int brow = idx / (BN / 4);
      const int bcol4 = (idx % (BN / 4)) * 4;
      *reinterpret_cast<float4*>(&Bs[brow][bcol4]) =
          *reinterpret_cast<const float4*>(&B[(size_t)(k0 + brow) * N + bcol4]);
    }
    __syncthreads();
#pragma unroll
    for (int kk = 0; kk < BK; ++kk) {
      float ra[TM], rb[TN];
#pragma unroll
      for (int i = 0; i < TM; i += 4)
        *reinterpret_cast<float4*>(&ra[i]) =
            *reinterpret_cast<const float4*>(&As[kk][ty * TM + i]);
#pragma unroll
      for (int j = 0; j < TN; j += 4)
        *reinterpret_cast<float4*>(&rb[j]) =
            *reinterpret_cast<const float4*>(&Bs[kk][tx * TN + j]);
#pragma unroll
      for (int i = 0; i < TM; ++i)
#pragma unroll
        for (int j = 0; j < TN; ++j) acc[i][j] += ra[i] * rb[j];
    }
    __syncthreads();
  }
#pragma unroll
  for (int i = 0; i < TM; ++i) {
    const int gr = rowBase + ty * TM + i;
    if (gr < M) {
      const float s = rowscale[gr];
#pragma unroll
      for (int j = 0; j < TN; j += 4) {
        float4 v = {acc[i][j] * s, acc[i][j + 1] * s, acc[i][j + 2] * s,
                    acc[i][j + 3] * s};
        *reinterpret_cast<float4*>(&C[(size_t)gr * N + tx * TN + j]) = v;
      }
    }
  }
}

// ---------------------------------------------------------------------------
// agg128: out[d] = RELU?( dinv[d]*(sum g[s] + g[d]) + bias ), C=128.
// Half-wave x float4; two halves take different edges; unroll 4 -> 8 edges
// in flight. Cross-half reduce via shfl_xor(32).
// ---------------------------------------------------------------------------
template <bool RELU>
__global__ __launch_bounds__(256) void agg128_k(const float* __restrict__ g,
                                                const int* __restrict__ rowptr,
                                                const int* __restrict__ csr,
                                                const float* __restrict__ dinv,
                                                const float* __restrict__ bias,
                                                float* __restrict__ hout, int n) {
  const int wid = (blockIdx.x * 256 + threadIdx.x) >> 6;
  if (wid >= n) return;
  const int lane = threadIdx.x & 63;
  const int half = lane >> 5;
  const size_t col = (size_t)(lane & 31) * 4;
  const float dd = dinv[wid];
  const int beg = rowptr[wid];
  const int end = rowptr[wid + 1];
  float4 acc = make_float4(0.f, 0.f, 0.f, 0.f);
  int e = beg;
  for (; e + 8 <= end; e += 8) {
    const int s0 = csr[e + 0 + half];
    const int s1 = csr[e + 2 + half];
    const int s2 = csr[e + 4 + half];
    const int s3 = csr[e + 6 + half];
    const float4 v0 = *reinterpret_cast<const float4*>(&g[(size_t)s0 * 128 + col]);
    const float4 v1 = *reinterpret_cast<const float4*>(&g[(size_t)s1 * 128 + col]);
    const float4 v2 = *reinterpret_cast<const float4*>(&g[(size_t)s2 * 128 + col]);
    const float4 v3 = *reinterpret_cast<const float4*>(&g[(size_t)s3 * 128 + col]);
    acc.x += (v0.x + v1.x) + (v2.x + v3.x);
    acc.y += (v0.y + v1.y) + (v2.y + v3.y);
    acc.z += (v0.z + v1.z) + (v2.z + v3.z);
    acc.w += (v0.w + v1.w) + (v2.w + v3.w);
  }
  for (; e + 2 <= end; e += 2) {
    const int s = csr[e + half];
    const float4 v = *reinterpret_cast<const float4*>(&g[(size_t)s * 128 + col]);
    acc.x += v.x;
    acc.y += v.y;
    acc.z += v.z;
    acc.w += v.w;
  }
  if (e < end && half == 0) {
    const int s = csr[e];
    const float4 v = *reinterpret_cast<const float4*>(&g[(size_t)s * 128 + col]);
    acc.x += v.x;
    acc.y += v.y;
    acc.z += v.z;
    acc.w += v.w;
  }
  acc.x += __shfl_xor(acc.x, 32);
  acc.y += __shfl_xor(acc.y, 32);
  acc.z += __shfl_xor(acc.z, 32);
  acc.w += __shfl_xor(acc.w, 32);
  if (half == 0) {
    const float4 sv = *reinterpret_cast<const float4*>(&g[(size_t)wid * 128 + col]);
    const float4 b = *reinterpret_cast<const float4*>(&bias[col]);
    float4 r;
    r.x = dd * (acc.x + sv.x) + b.x;
    r.y = dd * (acc.y + sv.y) + b.y;
    r.z = dd * (acc.z + sv.z) + b.z;
    r.w = dd * (acc.w + sv.w) + b.w;
    if (RELU) {
      r.x = fmaxf(r.x, 0.f);
      r.y = fmaxf(r.y, 0.f);
      r.z = fmaxf(r.z, 0.f);
      r.w = fmaxf(r.w, 0.f);
    }
    *reinterpret_cast<float4*>(&hout[(size_t)wid * 128 + col]) = r;
  }
}

// ---------------------------------------------------------------------------
// agg64: C=64. Quarter-wave x float4 -> 4 edges/step, unroll 4 -> 16 edges.
// ---------------------------------------------------------------------------
__global__ __launch_bounds__(256) void agg64_k(const float* __restrict__ g,
                                               const int* __restrict__ rowptr,
                                               const int* __restrict__ csr,
                                               const float* __restrict__ dinv,
                                               const float* __restrict__ bias,
                                               float* __restrict__ hout, int n) {
  const int wid = (blockIdx.x * 256 + threadIdx.x) >> 6;
  if (wid >= n) return;
  const int lane = threadIdx.x & 63;
  const int quad = lane >> 4;
  const size_t col = (size_t)(lane & 15) * 4;
  const float dd = dinv[wid];
  const int beg = rowptr[wid];
  const int end = rowptr[wid + 1];
  float4 acc = make_float4(0.f, 0.f, 0.f, 0.f);
  int e = beg;
  for (; e + 16 <= end; e += 16) {
    const int s0 = csr[e + 0 + quad];
    const int s1 = csr[e + 4 + quad];
    const int s2 = csr[e + 8 + quad];
    const int s3 = csr[e + 12 + quad];
    const float4 v0 = *reinterpret_cast<const float4*>(&g[(size_t)s0 * 64 + col]);
    const float4 v1 = *reinterpret_cast<const float4*>(&g[(size_t)s1 * 64 + col]);
    const float4 v2 = *reinterpret_cast<const float4*>(&g[(size_t)s2 * 64 + col]);
    const float4 v3 = *reinterpret_cast<const float4*>(&g[(size_t)s3 * 64 + col]);
    acc.x += (v0.x + v1.x) + (v2.x + v3.x);
    acc.y += (v0.y + v1.y) + (v2.y + v3.y);
    acc.z += (v0.z + v1.z) + (v2.z + v3.z);
    acc.w += (v0.w + v1.w) + (v2.w + v3.w);
  }
  for (; e + 4 <= end; e += 4) {
    const int s = csr[e + quad];
    const float4 v = *reinterpret_cast<const float4*>(&g[(size_t)s * 64 + col]);
    acc.x += v.x;
    acc.y += v.y;
    acc.z += v.z;
    acc.w += v.w;
  }
  const int r = end - e;  // 0..3
  if (quad < r) {
    const int s = csr[e + quad];
    const float4 v = *reinterpret_cast<const float4*>(&g[(size_t)s * 64 + col]);
    acc.x += v.x;
    acc.y += v.y;
    acc.z += v.z;
    acc.w += v.w;
  }
  acc.x += __shfl_xor(acc.x, 16);
  acc.y += __shfl_xor(acc.y, 16);
  acc.z += __shfl_xor(acc.z, 16);
  acc.w += __shfl_xor(acc.w, 16);
  acc.x += __shfl_xor(acc.x, 32);
  acc.y += __shfl_xor(acc.y, 32);
  acc.z += __shfl_xor(acc.z, 32);
  acc.w += __shfl_xor(acc.w, 32);
  if (quad == 0) {
    const float4 sv = *reinterpret_cast<const float4*>(&g[(size_t)wid * 64 + col]);
    const float4 b = *reinterpret_cast<const float4*>(&bias[col]);
    float4 res;
    res.x = dd * (acc.x + sv.x) + b.x;
    res.y = dd * (acc.y + sv.y) + b.y;
    res.z = dd * (acc.z + sv.z) + b.z;
    res.w = dd * (acc.w + sv.w) + b.w;
    *reinterpret_cast<float4*>(&hout[(size_t)wid * 64 + col]) = res;
  }
}

// ---------------------------------------------------------------------------
// Decode: 8 lanes per edge, 2x float4 per lane (2 loads in flight each for
// u and v), shuffle reduce width 8.
// ---------------------------------------------------------------------------
__global__ __launch_bounds__(256) void decode_k(const int* __restrict__ pos,
                                                const int* __restrict__ neg,
                                                const float* __restrict__ z,
                                                float* __restrict__ out, int EP) {
  const long long t = (long long)blockIdx.x * 256 + threadIdx.x;
  const long long e = t >> 3;
  const int lane = (int)(t & 7);
  if (e >= 2LL * EP) return;
  int u, v;
  if (e < EP) {
    u = pos[e];
    v = pos[EP + e];
  } else {
    u = neg[e - EP];
    v = neg[EP + (e - EP)];
  }
  const float* zu = &z[(size_t)u * 64 + lane * 8];
  const float* zv = &z[(size_t)v * 64 + lane * 8];
  const float4 a0 = *reinterpret_cast<const float4*>(zu);
  const float4 a1 = *reinterpret_cast<const float4*>(zu + 4);
  const float4 b0 = *reinterpret_cast<const float4*>(zv);
  const float4 b1 = *reinterpret_cast<const float4*>(zv + 4);
  float p = a0.x * b0.x + a0.y * b0.y + a0.z * b0.z + a0.w * b0.w +
            a1.x * b1.x + a1.y * b1.y + a1.z * b1.z + a1.w * b1.w;
#pragma unroll
  for (int off = 4; off > 0; off >>= 1) p += __shfl_down(p, off, 8);
  if (lane == 0) out[e] = p;
}

// ---------------------------------------------------------------------------

extern "C" void kernel_launch(void* const* d_in, const int* in_sizes, int n_in,
                              void* d_out, int out_size, void* d_ws, size_t ws_size,
                              hipStream_t stream) {
  const float* x = (const float*)d_in[0];
  const int* ei = (const int*)d_in[1];
  const int* pos = (const int*)d_in[2];
  const int* neg = (const int*)d_in[3];
  const float* W1 = (const float*)d_in[4];
  const float* b1 = (const float*)d_in[5];
  const float* W2 = (const float*)d_in[6];
  const float* b2 = (const float*)d_in[7];
  float* out = (float*)d_out;

  const int H = in_sizes[5];        // 128
  const int IN = in_sizes[4] / H;   // 256
  const int OUT = in_sizes[7];      // 64
  const int N = in_sizes[0] / IN;   // 100000
  const int E = in_sizes[1] / 2;    // 1600000
  const int EP = in_sizes[2] / 2;   // 500000

  char* ws = (char*)d_ws;
  size_t off = 0;
  auto carve = [&](size_t bytes) -> char* {
    char* p = ws + off;
    off += (bytes + 255) & ~(size_t)255;
    return p;
  };
  const int NBUK = (N + BUK_NODES - 1) >> BUK_SHIFT;  // 782

  float* dinvb = (float*)carve((size_t)N * 4);
  int* rowptr = (int*)carve((size_t)(N + 1) * 4);
  int* bhist = (int*)carve((size_t)NBUK * 4);
  int* bbase = (int*)carve((size_t)(NBUK + 1) * 4);
  int* bcur = (int*)carve((size_t)NBUK * 4);
  int* ebuf = (int*)carve((size_t)E * 4);
  int* csr = (int*)carve((size_t)E * 4);
  float* bufA = (float*)carve((size_t)N * H * 4);
  float* bufB = (float*)carve((size_t)N * H * 4);
  (void)ws_size;

  const int* srcp = ei;
  const int* dstp = ei + E;

  // --- CSR build via bucketing ---
  hipMemsetAsync(bhist, 0, (size_t)NBUK * 4, stream);
  b_hist_k<<<512, 256, 0, stream>>>(dstp, E, NBUK, bhist);
  b_scan_k<<<1, 256, 0, stream>>>(bhist, NBUK, bbase, bcur);
  b_scatter_k<<<(E + 8191) / 8192, 256, 0, stream>>>(srcp, dstp, E, NBUK, bcur, ebuf);
  b_build_k<<<NBUK, 128, 0, stream>>>(ebuf, bbase, N, NBUK, dinvb, rowptr, csr);

  // --- encode ---
  gemm_tiled<64, 128, 32, 8, 4>
      <<<(N + 63) / 64, 256, 0, stream>>>(x, W1, bufA, dinvb, N, IN, H);
  agg128_k<true><<<(N + 3) / 4, 256, 0, stream>>>(bufA, rowptr, csr, dinvb, b1,
                                                  bufB, N);
  gemm_tiled<64, 64, 32, 4, 4>
      <<<(N + 63) / 64, 256, 0, stream>>>(bufB, W2, bufA, dinvb, N, H, OUT);
  agg64_k<<<(N + 3) / 4, 256, 0, stream>>>(bufA, rowptr, csr, dinvb, b2, bufB, N);
  // --- decode ---
  const long long threads = 2LL * EP * 8;
  decode_k<<<(int)((threads + 255) / 256), 256, 0, stream>>>(pos, neg, bufB, out, EP);
}